// Round 6
// baseline (219.100 us; speedup 1.0000x reference)
//
#include <hip/hip_runtime.h>

// SSIM loss, fused. R6: barrier-free wave-autonomous design.
// R5 post-mortem: all pipes <25% busy -> barrier-serialization bound (8
// barrier-pairs/block, global loads inside the barrier interval). This
// version has NO __shared__ data and NO __syncthreads in the hot path:
// one wave spans the full 512-col width (lane owns 8 adjacent cols), rolling
// column sums live in registers (x, y, xy, xx+yy basis: 5 ops/touch), and the
// 5-col left/right window halo comes from neighbor lanes via shfl. Horizontal
// 11-tap = register sliding window. Waves fully independent; 4096 waves.

#define IMG_H 512
#define IMG_W 512
#define N_IMG 64
#define WSTRIP 8            // rows per wave
#define WAVES_PER_BLOCK 4
#define NTHREADS (64 * WAVES_PER_BLOCK)

__global__ __launch_bounds__(NTHREADS, 4) void ssim_kernel(const float* __restrict__ img1,
                                                           const float* __restrict__ img2,
                                                           float* __restrict__ ws) {
    const int t = threadIdx.x;
    const int lane = t & 63;
    const int w = t >> 6;
    const int b = blockIdx.y;
    const int r0 = (blockIdx.x * WAVES_PER_BLOCK + w) * WSTRIP;
    const float* __restrict__ p1 = img1 + (size_t)b * (IMG_H * IMG_W);
    const float* __restrict__ p2 = img2 + (size_t)b * (IMG_H * IMG_W);
    const int c0 = lane * 8;

    float Sx[8], Sy[8], Sxy[8], Sq[8];
#pragma unroll
    for (int j = 0; j < 8; ++j) { Sx[j] = 0.f; Sy[j] = 0.f; Sxy[j] = 0.f; Sq[j] = 0.f; }

    auto addrow = [&](int r) {
        const float* a = p1 + (size_t)r * IMG_W + c0;
        const float* bb = p2 + (size_t)r * IMG_W + c0;
        float4 xa = *(const float4*)a, xb = *(const float4*)(a + 4);
        float4 ya = *(const float4*)bb, yb = *(const float4*)(bb + 4);
        float xs[8] = {xa.x, xa.y, xa.z, xa.w, xb.x, xb.y, xb.z, xb.w};
        float ys[8] = {ya.x, ya.y, ya.z, ya.w, yb.x, yb.y, yb.z, yb.w};
#pragma unroll
        for (int j = 0; j < 8; ++j) {
            Sx[j] += xs[j];
            Sy[j] += ys[j];
            Sxy[j] = fmaf(xs[j], ys[j], Sxy[j]);
            Sq[j]  = fmaf(xs[j], xs[j], Sq[j]);
            Sq[j]  = fmaf(ys[j], ys[j], Sq[j]);
        }
    };
    auto subrow = [&](int r) {
        const float* a = p1 + (size_t)r * IMG_W + c0;
        const float* bb = p2 + (size_t)r * IMG_W + c0;
        float4 xa = *(const float4*)a, xb = *(const float4*)(a + 4);
        float4 ya = *(const float4*)bb, yb = *(const float4*)(bb + 4);
        float xs[8] = {xa.x, xa.y, xa.z, xa.w, xb.x, xb.y, xb.z, xb.w};
        float ys[8] = {ya.x, ya.y, ya.z, ya.w, yb.x, yb.y, yb.z, yb.w};
#pragma unroll
        for (int j = 0; j < 8; ++j) {
            Sx[j] -= xs[j];
            Sy[j] -= ys[j];
            Sxy[j] = fmaf(-xs[j], ys[j], Sxy[j]);
            Sq[j]  = fmaf(-xs[j], xs[j], Sq[j]);
            Sq[j]  = fmaf(-ys[j], ys[j], Sq[j]);
        }
    };

    // Warm vertical window for output row r0 (zero pad outside image).
    {
        int rlo = r0 - 5; if (rlo < 0) rlo = 0;
        int rhi = r0 + 5; if (rhi > IMG_H - 1) rhi = IMG_H - 1;
        for (int r = rlo; r <= rhi; ++r) addrow(r);
    }

    const bool lane_lo = (lane == 0);
    const bool lane_hi = (lane == 63);

    // Horizontal: gather 5-left/5-right halo via shfl, slide 11-tap window.
    auto hwin = [&](const float (&S)[8], float (&Wo)[8]) {
        float l[5], r[5];
#pragma unroll
        for (int k = 0; k < 5; ++k) {
            float v = __shfl_up(S[3 + k], 1, 64);    // col c0-5+k from lane-1
            l[k] = lane_lo ? 0.f : v;
        }
#pragma unroll
        for (int k = 0; k < 5; ++k) {
            float v = __shfl_down(S[k], 1, 64);      // col c0+8+k from lane+1
            r[k] = lane_hi ? 0.f : v;
        }
        float acc0 = ((l[0] + l[1]) + (l[2] + l[3])) +
                     ((l[4] + S[0]) + (S[1] + S[2])) +
                     ((S[3] + S[4]) + S[5]);
        Wo[0] = acc0;
        const float addv[7] = {S[6], S[7], r[0], r[1], r[2], r[3], r[4]};
        const float subv[7] = {l[0], l[1], l[2], l[3], l[4], S[0], S[1]};
        float wv = acc0;
#pragma unroll
        for (int k = 0; k < 7; ++k) { wv = (wv + addv[k]) - subv[k]; Wo[k + 1] = wv; }
    };

    constexpr float inv  = 1.0f / 121.0f;
    constexpr float inv2 = 2.0f / 121.0f;
    constexpr float C1c = 0.01f * 0.01f;
    constexpr float C2c = 0.03f * 0.03f;
    float acc = 0.0f;

    for (int rr = 0; rr < WSTRIP; ++rr) {
        const int r = r0 + rr;
        if (rr > 0) {
            int ri = r + 5, ro = r - 6;
            if (ri < IMG_H) addrow(ri);
            if (ro >= 0)    subrow(ro);
        }
        float Wx[8], Wy[8], Wxy[8], Wq[8];
        hwin(Sx, Wx); hwin(Sy, Wy); hwin(Sxy, Wxy); hwin(Sq, Wq);
#pragma unroll
        for (int k = 0; k < 8; ++k) {
            float mu1 = Wx[k] * inv, mu2 = Wy[k] * inv;
            float m12 = mu1 * mu2;
            float P = fmaf(mu1, mu1, mu2 * mu2);          // mu1^2 + mu2^2
            float m12_2 = m12 + m12;                       // 2*mu1*mu2
            float s2 = fmaf(Wxy[k], inv2, -m12_2);         // 2*sigma12
            float A = fmaf(Wq[k], inv, -P);                // sig1^2 + sig2^2
            float num = (m12_2 + C1c) * (s2 + C2c);
            float den = (P + C1c) * (A + C2c);
            acc += __fdividef(num, den);
        }
    }

    // Wave reduction -> one atomic per wave (4096 total, negligible).
#pragma unroll
    for (int off = 32; off > 0; off >>= 1) acc += __shfl_down(acc, off);
    if (lane == 0) atomicAdd(ws, acc);
}

__global__ void ssim_finalize(const float* __restrict__ ws, float* __restrict__ out) {
    constexpr float inv_n = 1.0f / (float)((size_t)N_IMG * IMG_H * IMG_W);
    out[0] = 1.0f - ws[0] * inv_n;
}

extern "C" void kernel_launch(void* const* d_in, const int* in_sizes, int n_in,
                              void* d_out, int out_size, void* d_ws, size_t ws_size,
                              hipStream_t stream) {
    const float* img1 = (const float*)d_in[0];
    const float* img2 = (const float*)d_in[1];
    float* out = (float*)d_out;
    float* ws = (float*)d_ws;

    hipMemsetAsync(ws, 0, sizeof(float), stream);

    dim3 grid(IMG_H / (WAVES_PER_BLOCK * WSTRIP), N_IMG);   // (16, 64) = 1024 blocks
    ssim_kernel<<<grid, NTHREADS, 0, stream>>>(img1, img2, ws);
    ssim_finalize<<<1, 1, 0, stream>>>(ws, out);
}